// Round 4
// baseline (590.848 us; speedup 1.0000x reference)
//
#include <hip/hip_runtime.h>
#include <math.h>

typedef __attribute__((ext_vector_type(8))) short short8;
typedef __attribute__((ext_vector_type(4))) float f32x4;

__device__ __forceinline__ unsigned short f2bf(float f) {
  unsigned int u = __float_as_uint(f);
  u += 0x7fffu + ((u >> 16) & 1u);
  return (unsigned short)(u >> 16);
}

// branch-free erf-based gelu (A&S 7.1.26, |err|<1.5e-7)
__device__ __forceinline__ float gelu_f(float v) {
  float xa = fabsf(v) * 0.70710678118f;
  float t = __builtin_amdgcn_rcpf(1.f + 0.3275911f * xa);
  float p = t * (0.254829592f +
            t * (-0.284496736f +
            t * (1.421413741f +
            t * (-1.453152027f + t * 1.061405429f))));
  float erfa = 1.f - p * __expf(-xa * xa);
  return 0.5f * v * (1.f + copysignf(erfa, v));
}

// async global->LDS, 16B per lane. LDS dst is wave-uniform base; HW deposits
// lane i at base + i*16. Global side addresses are per-lane arbitrary.
__device__ __forceinline__ void gll16(const unsigned short* g, unsigned short* l) {
  __builtin_amdgcn_global_load_lds(
      (const __attribute__((address_space(1))) unsigned int*)(uintptr_t)g,
      (__attribute__((address_space(3))) unsigned int*)(uintptr_t)l, 16, 0, 0);
}

// ---------------- fp32 -> bf16 conversion ----------------
__global__ __launch_bounds__(256) void cvt_f32_bf16(const float* __restrict__ in,
                                                    unsigned short* __restrict__ out,
                                                    int n4) {
  int i = blockIdx.x * 256 + threadIdx.x;
  if (i >= n4) return;
  float4 f = reinterpret_cast<const float4*>(in)[i];
  ushort4 o;
  o.x = f2bf(f.x); o.y = f2bf(f.y); o.z = f2bf(f.z); o.w = f2bf(f.w);
  reinterpret_cast<ushort4*>(out)[i] = o;
}

__global__ __launch_bounds__(256) void cvt4_f32_bf16(
    const float* __restrict__ a, const float* __restrict__ b,
    const float* __restrict__ c, const float* __restrict__ d,
    unsigned short* __restrict__ oa, unsigned short* __restrict__ ob,
    unsigned short* __restrict__ oc, unsigned short* __restrict__ od) {
  const float* in = (blockIdx.y == 0) ? a : (blockIdx.y == 1) ? b : (blockIdx.y == 2) ? c : d;
  unsigned short* out = (blockIdx.y == 0) ? oa : (blockIdx.y == 1) ? ob : (blockIdx.y == 2) ? oc : od;
  int i = blockIdx.x * 256 + threadIdx.x;
  float4 f = reinterpret_cast<const float4*>(in)[i];
  ushort4 o;
  o.x = f2bf(f.x); o.y = f2bf(f.y); o.z = f2bf(f.z); o.w = f2bf(f.w);
  reinterpret_cast<ushort4*>(out)[i] = o;
}

// ---------------- GEMM: C = A[M,K] * B[N,K]^T (m97 structure) ----------------
// SWAP=true: operands swapped -> lanes hold C rows, regs hold 4 consecutive
// C cols (vectorized epilogues).
// EPI 5 (swap):  fused QK. B rows 0..1023=Wq, 1024..2047=Wk.
//                -> bf16 [B,H,S,DH] (chunk 0 scaled 1/8).
// EPI 4 (!swap): V -> bf16 [B,H,DH,S] (pre-transposed, ushort4 s-pack).
// EPI 1 (swap):  f32 out = acc+bias+resid (float4).
// EPI 2 (swap):  bf16 out = gelu(acc+bias) (ushort4).
template <int EPI, bool SWAP>
__global__ __launch_bounds__(256) void gemm_nt(
    const unsigned short* __restrict__ A, const unsigned short* __restrict__ B,
    const float* __restrict__ bias, const float* __restrict__ bias_k,
    int K, int N, const float* __restrict__ resid,
    unsigned short* __restrict__ outb, float* __restrict__ outf) {
  __shared__ __align__(16) unsigned short As[128 * 32];  // unpadded: required by
  __shared__ __align__(16) unsigned short Bs[128 * 32];  // global_load_lds layout
  const int t = threadIdx.x;
  // M-group-8 swizzle: stride-8 block IDs (same XCD) share the A-tile row.
  const int lin = blockIdx.x + gridDim.x * blockIdx.y;
  const int rem = lin & (gridDim.x * 8 - 1);
  const int mt = (lin / (gridDim.x * 8)) * 8 + (rem & 7);
  const int tm = mt * 128, tn = (rem >> 3) * 128;
  const int lane = t & 63, wv = t >> 6;
  const int wr = wv >> 1, wc = wv & 1;
  const int l15 = lane & 15, quad = lane >> 4;
  const int srow = lane >> 2;
  const int scol = (lane & 3) << 3;

  const unsigned short* pa0 = &A[(size_t)(tm + (wv * 2) * 16 + srow) * K + scol];
  const unsigned short* pa1 = &A[(size_t)(tm + (wv * 2 + 1) * 16 + srow) * K + scol];
  const unsigned short* pb0 = &B[(size_t)(tn + (wv * 2) * 16 + srow) * K + scol];
  const unsigned short* pb1 = &B[(size_t)(tn + (wv * 2 + 1) * 16 + srow) * K + scol];
  unsigned short* la0 = &As[(wv * 2) * 512];
  unsigned short* la1 = &As[(wv * 2 + 1) * 512];
  unsigned short* lb0 = &Bs[(wv * 2) * 512];
  unsigned short* lb1 = &Bs[(wv * 2 + 1) * 512];

  const f32x4 zero = {0.f, 0.f, 0.f, 0.f};
  f32x4 acc[4][4];
#pragma unroll
  for (int i = 0; i < 4; ++i)
#pragma unroll
    for (int j = 0; j < 4; ++j) acc[i][j] = zero;

  for (int k0 = 0; k0 < K; k0 += 32) {
    __syncthreads();
    gll16(pa0, la0); pa0 += 32;
    gll16(pa1, la1); pa1 += 32;
    gll16(pb0, lb0); pb0 += 32;
    gll16(pb1, lb1); pb1 += 32;
    __syncthreads();  // vmcnt(0): staging complete
    short8 af[4], bfr[4];
#pragma unroll
    for (int i = 0; i < 4; ++i) {
      af[i] = *reinterpret_cast<const short8*>(&As[(wr * 64 + i * 16 + l15) * 32 + quad * 8]);
      bfr[i] = *reinterpret_cast<const short8*>(&Bs[(wc * 64 + i * 16 + l15) * 32 + quad * 8]);
    }
#pragma unroll
    for (int i = 0; i < 4; ++i)
#pragma unroll
      for (int j = 0; j < 4; ++j)
        acc[i][j] = SWAP
            ? __builtin_amdgcn_mfma_f32_16x16x32_bf16(bfr[j], af[i], acc[i][j], 0, 0, 0)
            : __builtin_amdgcn_mfma_f32_16x16x32_bf16(af[i], bfr[j], acc[i][j], 0, 0, 0);
  }

  if (SWAP) {
    // lane holds row = tm+wr*64+i*16+l15; regs hold cols col0..col0+3
#pragma unroll
    for (int i = 0; i < 4; ++i) {
      const int row = tm + wr * 64 + i * 16 + l15;
#pragma unroll
      for (int j = 0; j < 4; ++j) {
        const int col0 = tn + wc * 64 + j * 16 + quad * 4;
        if (EPI == 5) {
          const int chunk = col0 >> 10;          // 0=Q, 1=K (block-uniform)
          const int colc = col0 & 1023;
          const float4 b4 = *reinterpret_cast<const float4*>(
              &(chunk == 0 ? bias : bias_k)[colc]);
          const float sc = (chunk == 0) ? 0.125f : 1.f;
          const int h = colc >> 6, dh = colc & 63;
          const int b = row >> 10, s = row & 1023;
          ushort4 pk;
          pk.x = f2bf((acc[i][j][0] + b4.x) * sc);
          pk.y = f2bf((acc[i][j][1] + b4.y) * sc);
          pk.z = f2bf((acc[i][j][2] + b4.z) * sc);
          pk.w = f2bf((acc[i][j][3] + b4.w) * sc);
          *reinterpret_cast<ushort4*>(
              &outb[((size_t)chunk << 23) + (((size_t)((b << 4) + h)) << 16) + (s << 6) + dh]) = pk;
        } else if (EPI == 2) {
          const float4 b4 = *reinterpret_cast<const float4*>(&bias[col0]);
          ushort4 pk;
          pk.x = f2bf(gelu_f(acc[i][j][0] + b4.x));
          pk.y = f2bf(gelu_f(acc[i][j][1] + b4.y));
          pk.z = f2bf(gelu_f(acc[i][j][2] + b4.z));
          pk.w = f2bf(gelu_f(acc[i][j][3] + b4.w));
          *reinterpret_cast<ushort4*>(&outb[(size_t)row * (size_t)N + col0]) = pk;
        } else {  // EPI 1
          const float4 b4 = *reinterpret_cast<const float4*>(&bias[col0]);
          const size_t idx = (size_t)row * (size_t)N + col0;
          const float4 r4 = *reinterpret_cast<const float4*>(&resid[idx]);
          float4 o4;
          o4.x = acc[i][j][0] + b4.x + r4.x;
          o4.y = acc[i][j][1] + b4.y + r4.y;
          o4.z = acc[i][j][2] + b4.z + r4.z;
          o4.w = acc[i][j][3] + b4.w + r4.w;
          *reinterpret_cast<float4*>(&outf[idx]) = o4;
        }
      }
    }
  } else {
    // EPI 4: V epilogue — regs hold 4 consecutive tokens (s); pack for [b,h,dh,s]
#pragma unroll
    for (int i = 0; i < 4; ++i) {
#pragma unroll
      for (int j = 0; j < 4; ++j) {
        const int col = tn + wc * 64 + j * 16 + l15;
        const float bcol = bias[col];
        const int h = col >> 6, dh = col & 63;
        const int row0 = tm + wr * 64 + i * 16 + quad * 4;
        const int b = row0 >> 10, s0 = row0 & 1023;
        ushort4 pk;
        pk.x = f2bf(acc[i][j][0] + bcol);
        pk.y = f2bf(acc[i][j][1] + bcol);
        pk.z = f2bf(acc[i][j][2] + bcol);
        pk.w = f2bf(acc[i][j][3] + bcol);
        *reinterpret_cast<ushort4*>(
            &outb[(((size_t)((b << 4) + h)) << 16) + (dh << 10) + s0]) = pk;
      }
    }
  }
}

// ---------------- fused flash attention ----------------
// grid (B*H, S/64). Q pre-scaled by 1/8. V pre-transposed [b,h,dh,s].
// Fixed-shift softmax: p = exp(s - 8) (scores bounded; identical result).
__global__ __launch_bounds__(256) void attn_kernel(
    const unsigned short* __restrict__ Q, const unsigned short* __restrict__ Kc,
    const unsigned short* __restrict__ Vg, const int* __restrict__ mask,
    unsigned short* __restrict__ ctx) {
  __shared__ __align__(16) unsigned short Qs[64 * 64];
  __shared__ __align__(16) unsigned short Ks[64 * 64];
  __shared__ __align__(16) unsigned short Vs[64 * 64];  // V^T tile [dh][key]
  __shared__ __align__(16) unsigned short Ps[4 * 16 * 72];
  __shared__ float maskf[1024];
  const int t = threadIdx.x;
  const int bh = blockIdx.x;
  const int qt = blockIdx.y;
  const int b = bh >> 4, h = bh & 15;
  const int lane = t & 63, wv = t >> 6, l15 = lane & 15, quad = lane >> 4;
  const int lr = lane >> 3;              // deposit row within 8-row segment
  const int cs = (lane & 7) ^ lr;        // swizzled global column-group
  const unsigned short* Qp = Q + ((size_t)bh << 16);
  const unsigned short* Kp = Kc + ((size_t)bh << 16);
  const unsigned short* Vp = Vg + ((size_t)bh << 16);

  for (int i = t; i < 1024; i += 256)
    maskf[i] = mask[b * 1024 + i] ? -8.f : -INFINITY;
#pragma unroll
  for (int i = 0; i < 2; ++i) {
    const int seg = wv * 2 + i;
    gll16(&Qp[(qt * 64 + seg * 8 + lr) * 64 + cs * 8], &Qs[seg * 512]);
  }
  __syncthreads();
  const int sw0 = ((quad ^ (l15 & 7)) << 3);        // frag cols 0..31
  const int sw1 = (((quad + 4) ^ (l15 & 7)) << 3);  // frag cols 32..63
  const short8 qf0 = *reinterpret_cast<const short8*>(&Qs[(wv * 16 + l15) * 64 + sw0]);
  const short8 qf1 = *reinterpret_cast<const short8*>(&Qs[(wv * 16 + l15) * 64 + sw1]);

  const f32x4 zero = {0.f, 0.f, 0.f, 0.f};
  float ps[4] = {0.f, 0.f, 0.f, 0.f};
  f32x4 o[4];
#pragma unroll
  for (int j = 0; j < 4; ++j) o[j] = zero;

  unsigned short* Pw = &Ps[wv * 16 * 72];
  for (int kt = 0; kt < 16; ++kt) {
    __syncthreads();
#pragma unroll
    for (int i = 0; i < 2; ++i) {
      const int seg = wv * 2 + i;
      const int row = seg * 8 + lr;
      gll16(&Kp[(kt * 64 + row) * 64 + cs * 8], &Ks[seg * 512]);
      gll16(&Vp[row * 1024 + kt * 64 + cs * 8], &Vs[seg * 512]);
    }
    __syncthreads();

    f32x4 s4[4];
    float madd[4];
#pragma unroll
    for (int nt = 0; nt < 4; ++nt) {
      const int row = nt * 16 + l15;
      short8 kf0 = *reinterpret_cast<const short8*>(&Ks[row * 64 + sw0]);
      short8 kf1 = *reinterpret_cast<const short8*>(&Ks[row * 64 + sw1]);
      s4[nt] = __builtin_amdgcn_mfma_f32_16x16x32_bf16(qf0, kf0, zero, 0, 0, 0);
      s4[nt] = __builtin_amdgcn_mfma_f32_16x16x32_bf16(qf1, kf1, s4[nt], 0, 0, 0);
      madd[nt] = maskf[kt * 64 + nt * 16 + l15];
    }
#pragma unroll
    for (int nt = 0; nt < 4; ++nt) {
#pragma unroll
      for (int r = 0; r < 4; ++r) {
        float p = __expf(s4[nt][r] + madd[nt]);
        ps[r] += p;
        Pw[(quad * 4 + r) * 72 + nt * 16 + l15] = f2bf(p);
      }
    }
    short8 pf0 = *reinterpret_cast<const short8*>(&Pw[l15 * 72 + quad * 8]);
    short8 pf1 = *reinterpret_cast<const short8*>(&Pw[l15 * 72 + 32 + quad * 8]);
#pragma unroll
    for (int nt = 0; nt < 4; ++nt) {
      const int row = nt * 16 + l15;
      short8 vf0 = *reinterpret_cast<const short8*>(&Vs[row * 64 + sw0]);
      short8 vf1 = *reinterpret_cast<const short8*>(&Vs[row * 64 + sw1]);
      o[nt] = __builtin_amdgcn_mfma_f32_16x16x32_bf16(pf0, vf0, o[nt], 0, 0, 0);
      o[nt] = __builtin_amdgcn_mfma_f32_16x16x32_bf16(pf1, vf1, o[nt], 0, 0, 0);
    }
  }

#pragma unroll
  for (int r = 0; r < 4; ++r) {
#pragma unroll
    for (int off = 8; off >= 1; off >>= 1) ps[r] += __shfl_xor(ps[r], off, 64);
  }
#pragma unroll
  for (int r = 0; r < 4; ++r) {
    float inv = 1.f / ps[r];
    int srow = qt * 64 + wv * 16 + quad * 4 + r;
#pragma unroll
    for (int nt = 0; nt < 4; ++nt) {
      int dh = nt * 16 + l15;
      ctx[((size_t)b << 20) + ((size_t)srow << 10) + (h << 6) + dh] = f2bf(o[nt][r] * inv);
    }
  }
}

// ---------------- layer norm (block per row, D=1024) ----------------
__global__ __launch_bounds__(256) void ln_kernel(float* __restrict__ y,
                                                 const float* __restrict__ g,
                                                 const float* __restrict__ be,
                                                 unsigned short* __restrict__ hb) {
  __shared__ float sm[8];
  const int t = threadIdx.x;
  const size_t row = blockIdx.x;
  float* yr = y + (row << 10);
  float v[4];
#pragma unroll
  for (int i = 0; i < 4; ++i) v[i] = yr[t + (i << 8)];
  float s = v[0] + v[1] + v[2] + v[3];
#pragma unroll
  for (int off = 32; off >= 1; off >>= 1) s += __shfl_xor(s, off, 64);
  if ((t & 63) == 0) sm[t >> 6] = s;
  __syncthreads();
  float mu = (sm[0] + sm[1] + sm[2] + sm[3]) * (1.f / 1024.f);
  float q = 0.f;
#pragma unroll
  for (int i = 0; i < 4; ++i) { float d = v[i] - mu; q += d * d; }
#pragma unroll
  for (int off = 32; off >= 1; off >>= 1) q += __shfl_xor(q, off, 64);
  if ((t & 63) == 0) sm[4 + (t >> 6)] = q;
  __syncthreads();
  float var = (sm[4] + sm[5] + sm[6] + sm[7]) * (1.f / 1024.f);
  float rs = rsqrtf(var + 1e-12f);
#pragma unroll
  for (int i = 0; i < 4; ++i) {
    int c = t + (i << 8);
    float o = (v[i] - mu) * rs * g[c] + be[c];
    yr[c] = o;
    if (hb) hb[(row << 10) + c] = f2bf(o);
  }
}

extern "C" void kernel_launch(void* const* d_in, const int* in_sizes, int n_in,
                              void* d_out, int out_size, void* d_ws, size_t ws_size,
                              hipStream_t stream) {
  const float* x   = (const float*)d_in[0];
  const int*   msk = (const int*)d_in[1];
  const float* Wq  = (const float*)d_in[2];
  const float* bq  = (const float*)d_in[3];
  const float* Wk  = (const float*)d_in[4];
  const float* bk  = (const float*)d_in[5];
  const float* Wv  = (const float*)d_in[6];
  const float* bv  = (const float*)d_in[7];
  const float* Wo  = (const float*)d_in[8];
  const float* bo  = (const float*)d_in[9];
  const float* g1  = (const float*)d_in[10];
  const float* be1 = (const float*)d_in[11];
  const float* W1  = (const float*)d_in[12];
  const float* b1  = (const float*)d_in[13];
  const float* W2  = (const float*)d_in[14];
  const float* b2  = (const float*)d_in[15];
  const float* g2  = (const float*)d_in[16];
  const float* be2 = (const float*)d_in[17];
  float* out = (float*)d_out;

  unsigned short* Wqb = (unsigned short*)d_ws;   // Wq|Wk contiguous = fused QK B
  unsigned short* Wkb = Wqb + (1u << 20);
  unsigned short* Wvb = Wkb + (1u << 20);
  unsigned short* Wob = Wvb + (1u << 20);
  unsigned short* W1b = Wob + (1u << 20);
  unsigned short* W2b = W1b + (4u << 20);
  unsigned short* xb  = W2b + (4u << 20);
  unsigned short* qb  = xb + (8u << 20);   // q|k contiguous (chunk<<23)
  unsigned short* vb  = qb + (16u << 20);  // V stored [b,h,dh,s]
  unsigned short* ctx = xb;                // reuse (xb dead after QKV GEMMs)
  unsigned short* ffb = xb;                // 32M elems spanning xb+q+k+v
  float* y1 = (float*)(qb + (24u << 20));
  unsigned short* hb = (unsigned short*)(y1 + (8u << 20));

  dim3 blk(256);
  cvt4_f32_bf16<<<dim3(1024, 4), blk, 0, stream>>>(Wq, Wk, Wv, Wo, Wqb, Wkb, Wvb, Wob);
  cvt_f32_bf16<<<dim3(4096), blk, 0, stream>>>(W1, W1b, 1 << 20);
  cvt_f32_bf16<<<dim3(4096), blk, 0, stream>>>(W2, W2b, 1 << 20);
  cvt_f32_bf16<<<dim3(8192), blk, 0, stream>>>(x, xb, 1 << 21);
  // QK fused projection (N=2048, swapped/vectorized); V separate (transposed pack)
  gemm_nt<5, true><<<dim3(16, 64), blk, 0, stream>>>(xb, Wqb, bq, bk, 1024, 1024,
                                                     nullptr, qb, nullptr);
  gemm_nt<4, false><<<dim3(8, 64), blk, 0, stream>>>(xb, Wvb, bv, nullptr, 1024, 1024,
                                                     nullptr, vb, nullptr);
  attn_kernel<<<dim3(128, 16), blk, 0, stream>>>(qb, qb + (8u << 20), vb, msk, ctx);
  // output projection + residual
  gemm_nt<1, true><<<dim3(8, 64), blk, 0, stream>>>(ctx, Wob, bo, nullptr, 1024, 1024,
                                                    x, nullptr, y1);
  ln_kernel<<<dim3(8192), blk, 0, stream>>>(y1, g1, be1, hb);
  // FFN
  gemm_nt<2, true><<<dim3(32, 64), blk, 0, stream>>>(hb, W1b, b1, nullptr, 1024, 4096,
                                                     nullptr, ffb, nullptr);
  gemm_nt<1, true><<<dim3(8, 64), blk, 0, stream>>>(ffb, W2b, b2, nullptr, 4096, 1024,
                                                    y1, nullptr, out);
  ln_kernel<<<dim3(8192), blk, 0, stream>>>(out, g2, be2, nullptr);
}

// Round 5
// 568.503 us; speedup vs baseline: 1.0393x; 1.0393x over previous
//
#include <hip/hip_runtime.h>
#include <math.h>

typedef __attribute__((ext_vector_type(8))) short short8;
typedef __attribute__((ext_vector_type(4))) float f32x4;

__device__ __forceinline__ unsigned short f2bf(float f) {
  unsigned int u = __float_as_uint(f);
  u += 0x7fffu + ((u >> 16) & 1u);
  return (unsigned short)(u >> 16);
}

// branch-free erf-based gelu (A&S 7.1.26, |err|<1.5e-7)
__device__ __forceinline__ float gelu_f(float v) {
  float xa = fabsf(v) * 0.70710678118f;
  float t = __builtin_amdgcn_rcpf(1.f + 0.3275911f * xa);
  float p = t * (0.254829592f +
            t * (-0.284496736f +
            t * (1.421413741f +
            t * (-1.453152027f + t * 1.061405429f))));
  float erfa = 1.f - p * __expf(-xa * xa);
  return 0.5f * v * (1.f + copysignf(erfa, v));
}

// async global->LDS, 16B per lane. LDS dst is wave-uniform base; HW deposits
// lane i at base + i*16. Global side addresses are per-lane arbitrary.
__device__ __forceinline__ void gll16(const unsigned short* g, unsigned short* l) {
  __builtin_amdgcn_global_load_lds(
      (const __attribute__((address_space(1))) unsigned int*)(uintptr_t)g,
      (__attribute__((address_space(3))) unsigned int*)(uintptr_t)l, 16, 0, 0);
}

// ---------------- fp32 -> bf16 conversion ----------------
__global__ __launch_bounds__(256) void cvt_f32_bf16(const float* __restrict__ in,
                                                    unsigned short* __restrict__ out,
                                                    int n4) {
  int i = blockIdx.x * 256 + threadIdx.x;
  if (i >= n4) return;
  float4 f = reinterpret_cast<const float4*>(in)[i];
  ushort4 o;
  o.x = f2bf(f.x); o.y = f2bf(f.y); o.z = f2bf(f.z); o.w = f2bf(f.w);
  reinterpret_cast<ushort4*>(out)[i] = o;
}

__global__ __launch_bounds__(256) void cvt4_f32_bf16(
    const float* __restrict__ a, const float* __restrict__ b,
    const float* __restrict__ c, const float* __restrict__ d,
    unsigned short* __restrict__ oa, unsigned short* __restrict__ ob,
    unsigned short* __restrict__ oc, unsigned short* __restrict__ od) {
  const float* in = (blockIdx.y == 0) ? a : (blockIdx.y == 1) ? b : (blockIdx.y == 2) ? c : d;
  unsigned short* out = (blockIdx.y == 0) ? oa : (blockIdx.y == 1) ? ob : (blockIdx.y == 2) ? oc : od;
  int i = blockIdx.x * 256 + threadIdx.x;
  float4 f = reinterpret_cast<const float4*>(in)[i];
  ushort4 o;
  o.x = f2bf(f.x); o.y = f2bf(f.y); o.z = f2bf(f.z); o.w = f2bf(f.w);
  reinterpret_cast<ushort4*>(out)[i] = o;
}

// ---------------- GEMM: C = A[M,K] * B[N,K]^T ----------------
// 1-barrier double-buffered K-loop: prefetch tile k+1 while computing tile k.
// SWAP=true: mfma(B,A) -> lanes hold C rows, regs hold 4 consecutive C cols.
// EPI 5 (swap):  fused QK -> bf16 [B,H,S,DH] (chunk 0 scaled 1/8)
// EPI 4 (!swap): V -> bf16 [B,H,DH,S] (pre-transposed ushort4 s-pack)
// EPI 1 (swap):  f32 out = acc+bias+resid (float4)
// EPI 2 (swap):  bf16 out = gelu(acc+bias) (ushort4)
template <int EPI, bool SWAP>
__global__ __launch_bounds__(256) void gemm_nt(
    const unsigned short* __restrict__ A, const unsigned short* __restrict__ B,
    const float* __restrict__ bias, const float* __restrict__ bias_k,
    int K, int N, const float* __restrict__ resid,
    unsigned short* __restrict__ outb, float* __restrict__ outf) {
  __shared__ __align__(16) unsigned short As[2][128 * 32];
  __shared__ __align__(16) unsigned short Bs[2][128 * 32];
  const int t = threadIdx.x;
  const int tm = blockIdx.y * 128, tn = blockIdx.x * 128;  // x-fast raster
  const int lane = t & 63, wv = t >> 6;
  const int wr = wv >> 1, wc = wv & 1;
  const int l15 = lane & 15, quad = lane >> 4;
  const int srow = lane >> 2;
  const int scol = (lane & 3) << 3;

  const unsigned short* pa0 = &A[(size_t)(tm + wv * 32 + srow) * K + scol];
  const unsigned short* pa1 = &A[(size_t)(tm + wv * 32 + 16 + srow) * K + scol];
  const unsigned short* pb0 = &B[(size_t)(tn + wv * 32 + srow) * K + scol];
  const unsigned short* pb1 = &B[(size_t)(tn + wv * 32 + 16 + srow) * K + scol];
  unsigned short* la0 = &As[0][(wv * 2) * 512];
  unsigned short* la1 = &As[0][(wv * 2 + 1) * 512];
  unsigned short* lb0 = &Bs[0][(wv * 2) * 512];
  unsigned short* lb1 = &Bs[0][(wv * 2 + 1) * 512];

  const f32x4 zero = {0.f, 0.f, 0.f, 0.f};
  f32x4 acc[4][4];
#pragma unroll
  for (int i = 0; i < 4; ++i)
#pragma unroll
    for (int j = 0; j < 4; ++j) acc[i][j] = zero;

  // preload tile 0 into buffer 0
  gll16(pa0, la0); pa0 += 32;
  gll16(pa1, la1); pa1 += 32;
  gll16(pb0, lb0); pb0 += 32;
  gll16(pb1, lb1); pb1 += 32;

  const int nIter = K >> 5;
  for (int it = 0; it < nIter; ++it) {
    __syncthreads();  // vmcnt drain: deposits for this buffer landed (all waves)
    const int cur = (it & 1) * 4096;
    const int nxt = 4096 - cur;
    if (it + 1 < nIter) {  // prefetch k+1 into other buffer, in flight during MFMA
      gll16(pa0, la0 + nxt); pa0 += 32;
      gll16(pa1, la1 + nxt); pa1 += 32;
      gll16(pb0, lb0 + nxt); pb0 += 32;
      gll16(pb1, lb1 + nxt); pb1 += 32;
    }
    short8 af[4], bfr[4];
#pragma unroll
    for (int i = 0; i < 4; ++i) {
      af[i] = *reinterpret_cast<const short8*>(&As[0][cur + (wr * 64 + i * 16 + l15) * 32 + quad * 8]);
      bfr[i] = *reinterpret_cast<const short8*>(&Bs[0][cur + (wc * 64 + i * 16 + l15) * 32 + quad * 8]);
    }
#pragma unroll
    for (int i = 0; i < 4; ++i)
#pragma unroll
      for (int j = 0; j < 4; ++j)
        acc[i][j] = SWAP
            ? __builtin_amdgcn_mfma_f32_16x16x32_bf16(bfr[j], af[i], acc[i][j], 0, 0, 0)
            : __builtin_amdgcn_mfma_f32_16x16x32_bf16(af[i], bfr[j], acc[i][j], 0, 0, 0);
  }

  if (SWAP) {
#pragma unroll
    for (int i = 0; i < 4; ++i) {
      const int row = tm + wr * 64 + i * 16 + l15;
#pragma unroll
      for (int j = 0; j < 4; ++j) {
        const int col0 = tn + wc * 64 + j * 16 + quad * 4;
        if (EPI == 5) {
          const int chunk = col0 >> 10;          // 0=Q, 1=K (block-uniform)
          const int colc = col0 & 1023;
          const float4 b4 = *reinterpret_cast<const float4*>(
              &(chunk == 0 ? bias : bias_k)[colc]);
          const float sc = (chunk == 0) ? 0.125f : 1.f;
          const int h = colc >> 6, dh = colc & 63;
          const int b = row >> 10, s = row & 1023;
          ushort4 pk;
          pk.x = f2bf((acc[i][j][0] + b4.x) * sc);
          pk.y = f2bf((acc[i][j][1] + b4.y) * sc);
          pk.z = f2bf((acc[i][j][2] + b4.z) * sc);
          pk.w = f2bf((acc[i][j][3] + b4.w) * sc);
          *reinterpret_cast<ushort4*>(
              &outb[((size_t)chunk << 23) + (((size_t)((b << 4) + h)) << 16) + (s << 6) + dh]) = pk;
        } else if (EPI == 2) {
          const float4 b4 = *reinterpret_cast<const float4*>(&bias[col0]);
          ushort4 pk;
          pk.x = f2bf(gelu_f(acc[i][j][0] + b4.x));
          pk.y = f2bf(gelu_f(acc[i][j][1] + b4.y));
          pk.z = f2bf(gelu_f(acc[i][j][2] + b4.z));
          pk.w = f2bf(gelu_f(acc[i][j][3] + b4.w));
          *reinterpret_cast<ushort4*>(&outb[(size_t)row * (size_t)N + col0]) = pk;
        } else {  // EPI 1
          const float4 b4 = *reinterpret_cast<const float4*>(&bias[col0]);
          const size_t idx = (size_t)row * (size_t)N + col0;
          const float4 r4 = *reinterpret_cast<const float4*>(&resid[idx]);
          float4 o4;
          o4.x = acc[i][j][0] + b4.x + r4.x;
          o4.y = acc[i][j][1] + b4.y + r4.y;
          o4.z = acc[i][j][2] + b4.z + r4.z;
          o4.w = acc[i][j][3] + b4.w + r4.w;
          *reinterpret_cast<float4*>(&outf[idx]) = o4;
        }
      }
    }
  } else {
    // EPI 4: V epilogue — regs hold 4 consecutive tokens (s); pack for [b,h,dh,s]
#pragma unroll
    for (int i = 0; i < 4; ++i) {
#pragma unroll
      for (int j = 0; j < 4; ++j) {
        const int col = tn + wc * 64 + j * 16 + l15;
        const float bcol = bias[col];
        const int h = col >> 6, dh = col & 63;
        const int row0 = tm + wr * 64 + i * 16 + quad * 4;
        const int b = row0 >> 10, s0 = row0 & 1023;
        ushort4 pk;
        pk.x = f2bf(acc[i][j][0] + bcol);
        pk.y = f2bf(acc[i][j][1] + bcol);
        pk.z = f2bf(acc[i][j][2] + bcol);
        pk.w = f2bf(acc[i][j][3] + bcol);
        *reinterpret_cast<ushort4*>(
            &outb[(((size_t)((b << 4) + h)) << 16) + (dh << 10) + s0]) = pk;
      }
    }
  }
}

// ---------------- fused flash attention ----------------
// grid (B*H, S/64). Q pre-scaled by 1/8. V pre-transposed [b,h,dh,s].
// Fixed-shift softmax: p = exp(s - 8) (scores bounded; identical result).
// 1-barrier double-buffered K/V staging.
__global__ __launch_bounds__(256) void attn_kernel(
    const unsigned short* __restrict__ Q, const unsigned short* __restrict__ Kc,
    const unsigned short* __restrict__ Vg, const int* __restrict__ mask,
    unsigned short* __restrict__ ctx) {
  __shared__ __align__(16) unsigned short Qs[64 * 64];
  __shared__ __align__(16) unsigned short Ks[2][64 * 64];
  __shared__ __align__(16) unsigned short Vs[2][64 * 64];  // V^T tile [dh][key]
  __shared__ __align__(16) unsigned short Ps[4 * 16 * 72];
  __shared__ float maskf[1024];
  const int t = threadIdx.x;
  const int bh = blockIdx.x;
  const int qt = blockIdx.y;
  const int b = bh >> 4, h = bh & 15;
  const int lane = t & 63, wv = t >> 6, l15 = lane & 15, quad = lane >> 4;
  const int lr = lane >> 3;              // deposit row within 8-row segment
  const int cs = (lane & 7) ^ lr;        // swizzled global column-group
  const unsigned short* Qp = Q + ((size_t)bh << 16);
  const unsigned short* Kp = Kc + ((size_t)bh << 16);
  const unsigned short* Vp = Vg + ((size_t)bh << 16);
  const int seg0 = wv * 2, seg1 = wv * 2 + 1;
  const int r0 = seg0 * 8 + lr, r1 = seg1 * 8 + lr;

  for (int i = t; i < 1024; i += 256)
    maskf[i] = mask[b * 1024 + i] ? -8.f : -INFINITY;
#pragma unroll
  for (int i = 0; i < 2; ++i) {
    const int seg = wv * 2 + i;
    gll16(&Qp[(qt * 64 + seg * 8 + lr) * 64 + cs * 8], &Qs[seg * 512]);
  }
  // preload kt=0 K/V into buffer 0
  gll16(&Kp[r0 * 64 + cs * 8], &Ks[0][seg0 * 512]);
  gll16(&Kp[r1 * 64 + cs * 8], &Ks[0][seg1 * 512]);
  gll16(&Vp[r0 * 1024 + cs * 8], &Vs[0][seg0 * 512]);
  gll16(&Vp[r1 * 1024 + cs * 8], &Vs[0][seg1 * 512]);
  __syncthreads();
  const int sw0 = ((quad ^ (l15 & 7)) << 3);        // frag cols 0..31
  const int sw1 = (((quad + 4) ^ (l15 & 7)) << 3);  // frag cols 32..63
  const short8 qf0 = *reinterpret_cast<const short8*>(&Qs[(wv * 16 + l15) * 64 + sw0]);
  const short8 qf1 = *reinterpret_cast<const short8*>(&Qs[(wv * 16 + l15) * 64 + sw1]);

  const f32x4 zero = {0.f, 0.f, 0.f, 0.f};
  float ps[4] = {0.f, 0.f, 0.f, 0.f};
  f32x4 o[4];
#pragma unroll
  for (int j = 0; j < 4; ++j) o[j] = zero;

  unsigned short* Pw = &Ps[wv * 16 * 72];
  for (int kt = 0; kt < 16; ++kt) {
    const int cur = kt & 1;
    if (kt < 15) {  // prefetch next K/V tile into other buffer
      const int nb = cur ^ 1;
      gll16(&Kp[((kt + 1) * 64 + r0) * 64 + cs * 8], &Ks[nb][seg0 * 512]);
      gll16(&Kp[((kt + 1) * 64 + r1) * 64 + cs * 8], &Ks[nb][seg1 * 512]);
      gll16(&Vp[r0 * 1024 + (kt + 1) * 64 + cs * 8], &Vs[nb][seg0 * 512]);
      gll16(&Vp[r1 * 1024 + (kt + 1) * 64 + cs * 8], &Vs[nb][seg1 * 512]);
    }

    f32x4 s4[4];
    float madd[4];
#pragma unroll
    for (int nt = 0; nt < 4; ++nt) {
      const int row = nt * 16 + l15;
      short8 kf0 = *reinterpret_cast<const short8*>(&Ks[cur][row * 64 + sw0]);
      short8 kf1 = *reinterpret_cast<const short8*>(&Ks[cur][row * 64 + sw1]);
      s4[nt] = __builtin_amdgcn_mfma_f32_16x16x32_bf16(qf0, kf0, zero, 0, 0, 0);
      s4[nt] = __builtin_amdgcn_mfma_f32_16x16x32_bf16(qf1, kf1, s4[nt], 0, 0, 0);
      madd[nt] = maskf[kt * 64 + nt * 16 + l15];
    }
#pragma unroll
    for (int nt = 0; nt < 4; ++nt) {
#pragma unroll
      for (int r = 0; r < 4; ++r) {
        float p = __expf(s4[nt][r] + madd[nt]);
        ps[r] += p;
        Pw[(quad * 4 + r) * 72 + nt * 16 + l15] = f2bf(p);
      }
    }
    short8 pf0 = *reinterpret_cast<const short8*>(&Pw[l15 * 72 + quad * 8]);
    short8 pf1 = *reinterpret_cast<const short8*>(&Pw[l15 * 72 + 32 + quad * 8]);
#pragma unroll
    for (int nt = 0; nt < 4; ++nt) {
      const int row = nt * 16 + l15;
      short8 vf0 = *reinterpret_cast<const short8*>(&Vs[cur][row * 64 + sw0]);
      short8 vf1 = *reinterpret_cast<const short8*>(&Vs[cur][row * 64 + sw1]);
      o[nt] = __builtin_amdgcn_mfma_f32_16x16x32_bf16(pf0, vf0, o[nt], 0, 0, 0);
      o[nt] = __builtin_amdgcn_mfma_f32_16x16x32_bf16(pf1, vf1, o[nt], 0, 0, 0);
    }
    __syncthreads();  // next-buffer deposits landed (all waves); this tile's reads done
  }

#pragma unroll
  for (int r = 0; r < 4; ++r) {
#pragma unroll
    for (int off = 8; off >= 1; off >>= 1) ps[r] += __shfl_xor(ps[r], off, 64);
  }
#pragma unroll
  for (int r = 0; r < 4; ++r) {
    float inv = 1.f / ps[r];
    int srow = qt * 64 + wv * 16 + quad * 4 + r;
#pragma unroll
    for (int nt = 0; nt < 4; ++nt) {
      int dh = nt * 16 + l15;
      ctx[((size_t)b << 20) + ((size_t)srow << 10) + (h << 6) + dh] = f2bf(o[nt][r] * inv);
    }
  }
}

// ---------------- layer norm (block per row, D=1024) ----------------
__global__ __launch_bounds__(256) void ln_kernel(float* __restrict__ y,
                                                 const float* __restrict__ g,
                                                 const float* __restrict__ be,
                                                 unsigned short* __restrict__ hb) {
  __shared__ float sm[8];
  const int t = threadIdx.x;
  const size_t row = blockIdx.x;
  float* yr = y + (row << 10);
  float v[4];
#pragma unroll
  for (int i = 0; i < 4; ++i) v[i] = yr[t + (i << 8)];
  float s = v[0] + v[1] + v[2] + v[3];
#pragma unroll
  for (int off = 32; off >= 1; off >>= 1) s += __shfl_xor(s, off, 64);
  if ((t & 63) == 0) sm[t >> 6] = s;
  __syncthreads();
  float mu = (sm[0] + sm[1] + sm[2] + sm[3]) * (1.f / 1024.f);
  float q = 0.f;
#pragma unroll
  for (int i = 0; i < 4; ++i) { float d = v[i] - mu; q += d * d; }
#pragma unroll
  for (int off = 32; off >= 1; off >>= 1) q += __shfl_xor(q, off, 64);
  if ((t & 63) == 0) sm[4 + (t >> 6)] = q;
  __syncthreads();
  float var = (sm[4] + sm[5] + sm[6] + sm[7]) * (1.f / 1024.f);
  float rs = rsqrtf(var + 1e-12f);
#pragma unroll
  for (int i = 0; i < 4; ++i) {
    int c = t + (i << 8);
    float o = (v[i] - mu) * rs * g[c] + be[c];
    yr[c] = o;
    if (hb) hb[(row << 10) + c] = f2bf(o);
  }
}

extern "C" void kernel_launch(void* const* d_in, const int* in_sizes, int n_in,
                              void* d_out, int out_size, void* d_ws, size_t ws_size,
                              hipStream_t stream) {
  const float* x   = (const float*)d_in[0];
  const int*   msk = (const int*)d_in[1];
  const float* Wq  = (const float*)d_in[2];
  const float* bq  = (const float*)d_in[3];
  const float* Wk  = (const float*)d_in[4];
  const float* bk  = (const float*)d_in[5];
  const float* Wv  = (const float*)d_in[6];
  const float* bv  = (const float*)d_in[7];
  const float* Wo  = (const float*)d_in[8];
  const float* bo  = (const float*)d_in[9];
  const float* g1  = (const float*)d_in[10];
  const float* be1 = (const float*)d_in[11];
  const float* W1  = (const float*)d_in[12];
  const float* b1  = (const float*)d_in[13];
  const float* W2  = (const float*)d_in[14];
  const float* b2  = (const float*)d_in[15];
  const float* g2  = (const float*)d_in[16];
  const float* be2 = (const float*)d_in[17];
  float* out = (float*)d_out;

  unsigned short* Wqb = (unsigned short*)d_ws;   // Wq|Wk contiguous = fused QK B
  unsigned short* Wkb = Wqb + (1u << 20);
  unsigned short* Wvb = Wkb + (1u << 20);
  unsigned short* Wob = Wvb + (1u << 20);
  unsigned short* W1b = Wob + (1u << 20);
  unsigned short* W2b = W1b + (4u << 20);
  unsigned short* xb  = W2b + (4u << 20);
  unsigned short* qb  = xb + (8u << 20);   // q|k contiguous (chunk<<23)
  unsigned short* vb  = qb + (16u << 20);  // V stored [b,h,dh,s]
  unsigned short* ctx = xb;                // reuse (xb dead after QKV GEMMs)
  unsigned short* ffb = xb;                // 32M elems spanning xb+q+k+v
  float* y1 = (float*)(qb + (24u << 20));
  unsigned short* hb = (unsigned short*)(y1 + (8u << 20));

  dim3 blk(256);
  cvt4_f32_bf16<<<dim3(1024, 4), blk, 0, stream>>>(Wq, Wk, Wv, Wo, Wqb, Wkb, Wvb, Wob);
  cvt_f32_bf16<<<dim3(4096), blk, 0, stream>>>(W1, W1b, 1 << 20);
  cvt_f32_bf16<<<dim3(4096), blk, 0, stream>>>(W2, W2b, 1 << 20);
  cvt_f32_bf16<<<dim3(8192), blk, 0, stream>>>(x, xb, 1 << 21);
  // QK fused projection (N=2048, swapped/vectorized); V separate (transposed pack)
  gemm_nt<5, true><<<dim3(16, 64), blk, 0, stream>>>(xb, Wqb, bq, bk, 1024, 1024,
                                                     nullptr, qb, nullptr);
  gemm_nt<4, false><<<dim3(8, 64), blk, 0, stream>>>(xb, Wvb, bv, nullptr, 1024, 1024,
                                                     nullptr, vb, nullptr);
  attn_kernel<<<dim3(128, 16), blk, 0, stream>>>(qb, qb + (8u << 20), vb, msk, ctx);
  // output projection + residual
  gemm_nt<1, true><<<dim3(8, 64), blk, 0, stream>>>(ctx, Wob, bo, nullptr, 1024, 1024,
                                                    x, nullptr, y1);
  ln_kernel<<<dim3(8192), blk, 0, stream>>>(y1, g1, be1, hb);
  // FFN
  gemm_nt<2, true><<<dim3(32, 64), blk, 0, stream>>>(hb, W1b, b1, nullptr, 1024, 4096,
                                                     nullptr, ffb, nullptr);
  gemm_nt<1, true><<<dim3(8, 64), blk, 0, stream>>>(ffb, W2b, b2, nullptr, 4096, 1024,
                                                    y1, nullptr, out);
  ln_kernel<<<dim3(8192), blk, 0, stream>>>(out, g2, be2, nullptr);
}

// Round 6
// 531.024 us; speedup vs baseline: 1.1127x; 1.0706x over previous
//
#include <hip/hip_runtime.h>
#include <math.h>

typedef __attribute__((ext_vector_type(8))) short short8;
typedef __attribute__((ext_vector_type(4))) float f32x4;

__device__ __forceinline__ unsigned short f2bf(float f) {
  unsigned int u = __float_as_uint(f);
  u += 0x7fffu + ((u >> 16) & 1u);
  return (unsigned short)(u >> 16);
}

// branch-free erf-based gelu (A&S 7.1.26, |err|<1.5e-7)
__device__ __forceinline__ float gelu_f(float v) {
  float xa = fabsf(v) * 0.70710678118f;
  float t = __builtin_amdgcn_rcpf(1.f + 0.3275911f * xa);
  float p = t * (0.254829592f +
            t * (-0.284496736f +
            t * (1.421413741f +
            t * (-1.453152027f + t * 1.061405429f))));
  float erfa = 1.f - p * __expf(-xa * xa);
  return 0.5f * v * (1.f + copysignf(erfa, v));
}

// async global->LDS, 16B per lane. LDS dst is wave-uniform base; HW deposits
// lane i at base + i*16. Global side addresses are per-lane arbitrary.
__device__ __forceinline__ void gll16(const unsigned short* g, unsigned short* l) {
  __builtin_amdgcn_global_load_lds(
      (const __attribute__((address_space(1))) unsigned int*)(uintptr_t)g,
      (__attribute__((address_space(3))) unsigned int*)(uintptr_t)l, 16, 0, 0);
}

// ---------------- all fp32 -> bf16 conversions in ONE dispatch ----------------
// regions (blocks of 256 float4): [0,4096) Wq|Wk|Wv|Wo, [4096,8192) W1,
// [8192,12288) W2, [12288,20480) x. ws outputs are contiguous.
__global__ __launch_bounds__(256) void cvt_all(
    const float* __restrict__ Wq, const float* __restrict__ Wk,
    const float* __restrict__ Wv, const float* __restrict__ Wo,
    const float* __restrict__ W1, const float* __restrict__ W2,
    const float* __restrict__ x, unsigned short* __restrict__ ws) {
  const int bi = blockIdx.x;
  const float* in;
  unsigned short* out;
  int i;
  if (bi < 4096) {
    const int m = bi >> 10;
    in = (m == 0) ? Wq : (m == 1) ? Wk : (m == 2) ? Wv : Wo;
    out = ws + (size_t)m * (1u << 20);
    i = (bi & 1023) * 256 + threadIdx.x;
  } else if (bi < 8192) {
    in = W1; out = ws + (4u << 20); i = (bi - 4096) * 256 + threadIdx.x;
  } else if (bi < 12288) {
    in = W2; out = ws + (8u << 20); i = (bi - 8192) * 256 + threadIdx.x;
  } else {
    in = x; out = ws + (12u << 20); i = (bi - 12288) * 256 + threadIdx.x;
  }
  float4 f = reinterpret_cast<const float4*>(in)[i];
  ushort4 o;
  o.x = f2bf(f.x); o.y = f2bf(f.y); o.z = f2bf(f.z); o.w = f2bf(f.w);
  reinterpret_cast<ushort4*>(out)[i] = o;
}

// ---------------- GEMM: C = A[M,K] * B[N,K]^T ----------------
// 1-barrier double-buffered K-loop: prefetch tile k+1 while computing tile k.
// SWAP=true: mfma(B,A) -> lanes hold C rows, regs hold 4 consecutive C cols.
// EPI 5 (swap):  fused QK -> bf16 [B,H,S,DH] (chunk 0 scaled 1/8)
// EPI 4 (!swap): V -> bf16 [B,H,DH,S] (pre-transposed ushort4 s-pack)
// EPI 1 (swap):  f32 out = acc+bias+resid (float4)
// EPI 2 (swap):  bf16 out = gelu(acc+bias) (ushort4)
template <int EPI, bool SWAP>
__global__ __launch_bounds__(256) void gemm_nt(
    const unsigned short* __restrict__ A, const unsigned short* __restrict__ B,
    const float* __restrict__ bias, const float* __restrict__ bias_k,
    int K, int N, const float* __restrict__ resid,
    unsigned short* __restrict__ outb, float* __restrict__ outf) {
  __shared__ __align__(16) unsigned short As[2][128 * 32];
  __shared__ __align__(16) unsigned short Bs[2][128 * 32];
  const int t = threadIdx.x;
  const int tm = blockIdx.y * 128, tn = blockIdx.x * 128;  // x-fast raster
  const int lane = t & 63, wv = t >> 6;
  const int wr = wv >> 1, wc = wv & 1;
  const int l15 = lane & 15, quad = lane >> 4;
  const int srow = lane >> 2;
  const int scol = (lane & 3) << 3;

  const unsigned short* pa0 = &A[(size_t)(tm + wv * 32 + srow) * K + scol];
  const unsigned short* pa1 = &A[(size_t)(tm + wv * 32 + 16 + srow) * K + scol];
  const unsigned short* pb0 = &B[(size_t)(tn + wv * 32 + srow) * K + scol];
  const unsigned short* pb1 = &B[(size_t)(tn + wv * 32 + 16 + srow) * K + scol];
  unsigned short* la0 = &As[0][(wv * 2) * 512];
  unsigned short* la1 = &As[0][(wv * 2 + 1) * 512];
  unsigned short* lb0 = &Bs[0][(wv * 2) * 512];
  unsigned short* lb1 = &Bs[0][(wv * 2 + 1) * 512];

  const f32x4 zero = {0.f, 0.f, 0.f, 0.f};
  f32x4 acc[4][4];
#pragma unroll
  for (int i = 0; i < 4; ++i)
#pragma unroll
    for (int j = 0; j < 4; ++j) acc[i][j] = zero;

  // preload tile 0 into buffer 0
  gll16(pa0, la0); pa0 += 32;
  gll16(pa1, la1); pa1 += 32;
  gll16(pb0, lb0); pb0 += 32;
  gll16(pb1, lb1); pb1 += 32;

  const int nIter = K >> 5;
  for (int it = 0; it < nIter; ++it) {
    __syncthreads();  // vmcnt drain: deposits for this buffer landed (all waves)
    const int cur = (it & 1) * 4096;
    const int nxt = 4096 - cur;
    if (it + 1 < nIter) {  // prefetch k+1 into other buffer, in flight during MFMA
      gll16(pa0, la0 + nxt); pa0 += 32;
      gll16(pa1, la1 + nxt); pa1 += 32;
      gll16(pb0, lb0 + nxt); pb0 += 32;
      gll16(pb1, lb1 + nxt); pb1 += 32;
    }
    short8 af[4], bfr[4];
#pragma unroll
    for (int i = 0; i < 4; ++i) {
      af[i] = *reinterpret_cast<const short8*>(&As[0][cur + (wr * 64 + i * 16 + l15) * 32 + quad * 8]);
      bfr[i] = *reinterpret_cast<const short8*>(&Bs[0][cur + (wc * 64 + i * 16 + l15) * 32 + quad * 8]);
    }
#pragma unroll
    for (int i = 0; i < 4; ++i)
#pragma unroll
      for (int j = 0; j < 4; ++j)
        acc[i][j] = SWAP
            ? __builtin_amdgcn_mfma_f32_16x16x32_bf16(bfr[j], af[i], acc[i][j], 0, 0, 0)
            : __builtin_amdgcn_mfma_f32_16x16x32_bf16(af[i], bfr[j], acc[i][j], 0, 0, 0);
  }

  if (SWAP) {
#pragma unroll
    for (int i = 0; i < 4; ++i) {
      const int row = tm + wr * 64 + i * 16 + l15;
#pragma unroll
      for (int j = 0; j < 4; ++j) {
        const int col0 = tn + wc * 64 + j * 16 + quad * 4;
        if (EPI == 5) {
          const int chunk = col0 >> 10;          // 0=Q, 1=K (block-uniform)
          const int colc = col0 & 1023;
          const float4 b4 = *reinterpret_cast<const float4*>(
              &(chunk == 0 ? bias : bias_k)[colc]);
          const float sc = (chunk == 0) ? 0.125f : 1.f;
          const int h = colc >> 6, dh = colc & 63;
          const int b = row >> 10, s = row & 1023;
          ushort4 pk;
          pk.x = f2bf((acc[i][j][0] + b4.x) * sc);
          pk.y = f2bf((acc[i][j][1] + b4.y) * sc);
          pk.z = f2bf((acc[i][j][2] + b4.z) * sc);
          pk.w = f2bf((acc[i][j][3] + b4.w) * sc);
          *reinterpret_cast<ushort4*>(
              &outb[((size_t)chunk << 23) + (((size_t)((b << 4) + h)) << 16) + (s << 6) + dh]) = pk;
        } else if (EPI == 2) {
          const float4 b4 = *reinterpret_cast<const float4*>(&bias[col0]);
          ushort4 pk;
          pk.x = f2bf(gelu_f(acc[i][j][0] + b4.x));
          pk.y = f2bf(gelu_f(acc[i][j][1] + b4.y));
          pk.z = f2bf(gelu_f(acc[i][j][2] + b4.z));
          pk.w = f2bf(gelu_f(acc[i][j][3] + b4.w));
          *reinterpret_cast<ushort4*>(&outb[(size_t)row * (size_t)N + col0]) = pk;
        } else {  // EPI 1
          const float4 b4 = *reinterpret_cast<const float4*>(&bias[col0]);
          const size_t idx = (size_t)row * (size_t)N + col0;
          const float4 r4 = *reinterpret_cast<const float4*>(&resid[idx]);
          float4 o4;
          o4.x = acc[i][j][0] + b4.x + r4.x;
          o4.y = acc[i][j][1] + b4.y + r4.y;
          o4.z = acc[i][j][2] + b4.z + r4.z;
          o4.w = acc[i][j][3] + b4.w + r4.w;
          *reinterpret_cast<float4*>(&outf[idx]) = o4;
        }
      }
    }
  } else {
    // EPI 4: V epilogue — regs hold 4 consecutive tokens (s); pack for [b,h,dh,s]
#pragma unroll
    for (int i = 0; i < 4; ++i) {
#pragma unroll
      for (int j = 0; j < 4; ++j) {
        const int col = tn + wc * 64 + j * 16 + l15;
        const float bcol = bias[col];
        const int h = col >> 6, dh = col & 63;
        const int row0 = tm + wr * 64 + i * 16 + quad * 4;
        const int b = row0 >> 10, s0 = row0 & 1023;
        ushort4 pk;
        pk.x = f2bf(acc[i][j][0] + bcol);
        pk.y = f2bf(acc[i][j][1] + bcol);
        pk.z = f2bf(acc[i][j][2] + bcol);
        pk.w = f2bf(acc[i][j][3] + bcol);
        *reinterpret_cast<ushort4*>(
            &outb[(((size_t)((b << 4) + h)) << 16) + (dh << 10) + s0]) = pk;
      }
    }
  }
}

// ---------------- fused flash attention (128 Q-rows / block) ----------------
// grid (B*H, S/128). Q pre-scaled by 1/8. V pre-transposed [b,h,dh,s].
// Fixed-shift softmax: p = exp(s - 8) (scores bounded; identical result).
// Q fragments live in registers (no LDS, no staging barrier); each wave owns
// 32 Q-rows as two 16-row groups g; kf[] held in regs and reused across g.
// 1-barrier double-buffered K/V staging.
__global__ __launch_bounds__(256) void attn_kernel(
    const unsigned short* __restrict__ Q, const unsigned short* __restrict__ Kc,
    const unsigned short* __restrict__ Vg, const int* __restrict__ mask,
    unsigned short* __restrict__ ctx) {
  __shared__ __align__(16) unsigned short Ks[2][64 * 64];
  __shared__ __align__(16) unsigned short Vs[2][64 * 64];  // V^T tile [dh][key]
  __shared__ __align__(16) unsigned short Ps[4][16 * 72];  // wave-private P buf
  __shared__ float maskf[1024];
  const int t = threadIdx.x;
  const int bh = blockIdx.x;
  const int qt = blockIdx.y;
  const int b = bh >> 4, h = bh & 15;
  const int lane = t & 63, wv = t >> 6, l15 = lane & 15, quad = lane >> 4;
  const int lr = lane >> 3;              // deposit row within 8-row segment
  const int cs = (lane & 7) ^ lr;        // swizzled global column-group
  const unsigned short* Qp = Q + ((size_t)bh << 16);
  const unsigned short* Kp = Kc + ((size_t)bh << 16);
  const unsigned short* Vp = Vg + ((size_t)bh << 16);
  const int seg0 = wv * 2, seg1 = wv * 2 + 1;
  const int r0 = seg0 * 8 + lr, r1 = seg1 * 8 + lr;

  for (int i = t; i < 1024; i += 256)
    maskf[i] = mask[b * 1024 + i] ? -8.f : -INFINITY;

  // Q A-fragments straight from global (rows qt*128 + wv*32 + g*16 + l15)
  short8 qf[2][2];
#pragma unroll
  for (int g = 0; g < 2; ++g)
#pragma unroll
    for (int hh = 0; hh < 2; ++hh)
      qf[g][hh] = *reinterpret_cast<const short8*>(
          &Qp[(size_t)(qt * 128 + wv * 32 + g * 16 + l15) * 64 + hh * 32 + quad * 8]);

  // preload kt=0 K/V into buffer 0
  gll16(&Kp[r0 * 64 + cs * 8], &Ks[0][seg0 * 512]);
  gll16(&Kp[r1 * 64 + cs * 8], &Ks[0][seg1 * 512]);
  gll16(&Vp[r0 * 1024 + cs * 8], &Vs[0][seg0 * 512]);
  gll16(&Vp[r1 * 1024 + cs * 8], &Vs[0][seg1 * 512]);

  const int sw0 = ((quad ^ (l15 & 7)) << 3);        // frag cols 0..31
  const int sw1 = (((quad + 4) ^ (l15 & 7)) << 3);  // frag cols 32..63
  const f32x4 zero = {0.f, 0.f, 0.f, 0.f};
  float ps[2][4];
  f32x4 o[2][4];
#pragma unroll
  for (int g = 0; g < 2; ++g)
#pragma unroll
    for (int j = 0; j < 4; ++j) { o[g][j] = zero; ps[g][j] = 0.f; }

  unsigned short* Pw = Ps[wv];
  for (int kt = 0; kt < 16; ++kt) {
    __syncthreads();  // cur deposits landed (vmcnt drain); prior reads done
    const int cur = kt & 1;
    if (kt < 15) {  // prefetch next K/V tile into other buffer
      const int nb = cur ^ 1;
      gll16(&Kp[((kt + 1) * 64 + r0) * 64 + cs * 8], &Ks[nb][seg0 * 512]);
      gll16(&Kp[((kt + 1) * 64 + r1) * 64 + cs * 8], &Ks[nb][seg1 * 512]);
      gll16(&Vp[r0 * 1024 + (kt + 1) * 64 + cs * 8], &Vs[nb][seg0 * 512]);
      gll16(&Vp[r1 * 1024 + (kt + 1) * 64 + cs * 8], &Vs[nb][seg1 * 512]);
    }
    float madd[4];
    short8 kf[4][2];
#pragma unroll
    for (int nt = 0; nt < 4; ++nt) {
      const int row = (nt * 16 + l15) * 64;
      kf[nt][0] = *reinterpret_cast<const short8*>(&Ks[cur][row + sw0]);
      kf[nt][1] = *reinterpret_cast<const short8*>(&Ks[cur][row + sw1]);
      madd[nt] = maskf[kt * 64 + nt * 16 + l15];
    }
#pragma unroll
    for (int g = 0; g < 2; ++g) {
      f32x4 s4[4];
#pragma unroll
      for (int nt = 0; nt < 4; ++nt) {
        s4[nt] = __builtin_amdgcn_mfma_f32_16x16x32_bf16(qf[g][0], kf[nt][0], zero, 0, 0, 0);
        s4[nt] = __builtin_amdgcn_mfma_f32_16x16x32_bf16(qf[g][1], kf[nt][1], s4[nt], 0, 0, 0);
      }
#pragma unroll
      for (int nt = 0; nt < 4; ++nt) {
#pragma unroll
        for (int r = 0; r < 4; ++r) {
          float p = __expf(s4[nt][r] + madd[nt]);
          ps[g][r] += p;
          Pw[(quad * 4 + r) * 72 + nt * 16 + l15] = f2bf(p);
        }
      }
      // C-layout -> A-layout via wave-private LDS (in-order per-wave DS pipe)
      short8 pf0 = *reinterpret_cast<const short8*>(&Pw[l15 * 72 + quad * 8]);
      short8 pf1 = *reinterpret_cast<const short8*>(&Pw[l15 * 72 + 32 + quad * 8]);
#pragma unroll
      for (int nt = 0; nt < 4; ++nt) {
        const int row = (nt * 16 + l15) * 64;
        short8 vf0 = *reinterpret_cast<const short8*>(&Vs[cur][row + sw0]);
        short8 vf1 = *reinterpret_cast<const short8*>(&Vs[cur][row + sw1]);
        o[g][nt] = __builtin_amdgcn_mfma_f32_16x16x32_bf16(pf0, vf0, o[g][nt], 0, 0, 0);
        o[g][nt] = __builtin_amdgcn_mfma_f32_16x16x32_bf16(pf1, vf1, o[g][nt], 0, 0, 0);
      }
    }
  }

#pragma unroll
  for (int g = 0; g < 2; ++g)
#pragma unroll
    for (int r = 0; r < 4; ++r) {
      float v = ps[g][r];
#pragma unroll
      for (int off = 8; off >= 1; off >>= 1) v += __shfl_xor(v, off, 64);
      const float inv = 1.f / v;
      const int srow = qt * 128 + wv * 32 + g * 16 + quad * 4 + r;
#pragma unroll
      for (int nt = 0; nt < 4; ++nt) {
        const int dh = nt * 16 + l15;
        ctx[((size_t)b << 20) + ((size_t)srow << 10) + (h << 6) + dh] =
            f2bf(o[g][nt][r] * inv);
      }
    }
}

// ---------------- layer norm (block per row, D=1024) ----------------
__global__ __launch_bounds__(256) void ln_kernel(float* __restrict__ y,
                                                 const float* __restrict__ g,
                                                 const float* __restrict__ be,
                                                 unsigned short* __restrict__ hb) {
  __shared__ float sm[8];
  const int t = threadIdx.x;
  const size_t row = blockIdx.x;
  float* yr = y + (row << 10);
  float v[4];
#pragma unroll
  for (int i = 0; i < 4; ++i) v[i] = yr[t + (i << 8)];
  float s = v[0] + v[1] + v[2] + v[3];
#pragma unroll
  for (int off = 32; off >= 1; off >>= 1) s += __shfl_xor(s, off, 64);
  if ((t & 63) == 0) sm[t >> 6] = s;
  __syncthreads();
  float mu = (sm[0] + sm[1] + sm[2] + sm[3]) * (1.f / 1024.f);
  float q = 0.f;
#pragma unroll
  for (int i = 0; i < 4; ++i) { float d = v[i] - mu; q += d * d; }
#pragma unroll
  for (int off = 32; off >= 1; off >>= 1) q += __shfl_xor(q, off, 64);
  if ((t & 63) == 0) sm[4 + (t >> 6)] = q;
  __syncthreads();
  float var = (sm[4] + sm[5] + sm[6] + sm[7]) * (1.f / 1024.f);
  float rs = rsqrtf(var + 1e-12f);
#pragma unroll
  for (int i = 0; i < 4; ++i) {
    int c = t + (i << 8);
    float o = (v[i] - mu) * rs * g[c] + be[c];
    yr[c] = o;
    if (hb) hb[(row << 10) + c] = f2bf(o);
  }
}

extern "C" void kernel_launch(void* const* d_in, const int* in_sizes, int n_in,
                              void* d_out, int out_size, void* d_ws, size_t ws_size,
                              hipStream_t stream) {
  const float* x   = (const float*)d_in[0];
  const int*   msk = (const int*)d_in[1];
  const float* Wq  = (const float*)d_in[2];
  const float* bq  = (const float*)d_in[3];
  const float* Wk  = (const float*)d_in[4];
  const float* bk  = (const float*)d_in[5];
  const float* Wv  = (const float*)d_in[6];
  const float* bv  = (const float*)d_in[7];
  const float* Wo  = (const float*)d_in[8];
  const float* bo  = (const float*)d_in[9];
  const float* g1  = (const float*)d_in[10];
  const float* be1 = (const float*)d_in[11];
  const float* W1  = (const float*)d_in[12];
  const float* b1  = (const float*)d_in[13];
  const float* W2  = (const float*)d_in[14];
  const float* b2  = (const float*)d_in[15];
  const float* g2  = (const float*)d_in[16];
  const float* be2 = (const float*)d_in[17];
  float* out = (float*)d_out;

  unsigned short* Wqb = (unsigned short*)d_ws;   // Wq|Wk contiguous = fused QK B
  unsigned short* Wvb = Wqb + (2u << 20);
  unsigned short* Wob = Wvb + (1u << 20);
  unsigned short* W1b = Wob + (1u << 20);
  unsigned short* W2b = W1b + (4u << 20);
  unsigned short* xb  = W2b + (4u << 20);
  unsigned short* qb  = xb + (8u << 20);   // q|k contiguous (chunk<<23)
  unsigned short* vb  = qb + (16u << 20);  // V stored [b,h,dh,s]
  unsigned short* ctx = xb;                // reuse (xb dead after QKV GEMMs)
  unsigned short* ffb = xb;                // 32M elems spanning xb+q+k+v
  float* y1 = (float*)(qb + (24u << 20));
  unsigned short* hb = (unsigned short*)(y1 + (8u << 20));

  dim3 blk(256);
  // all conversions, one dispatch
  cvt_all<<<dim3(20480), blk, 0, stream>>>(Wq, Wk, Wv, Wo, W1, W2, x, (unsigned short*)d_ws);
  // QK fused projection (N=2048, swapped/vectorized); V separate (transposed pack)
  gemm_nt<5, true><<<dim3(16, 64), blk, 0, stream>>>(xb, Wqb, bq, bk, 1024, 1024,
                                                     nullptr, qb, nullptr);
  gemm_nt<4, false><<<dim3(8, 64), blk, 0, stream>>>(xb, Wvb, bv, nullptr, 1024, 1024,
                                                     nullptr, vb, nullptr);
  attn_kernel<<<dim3(128, 8), blk, 0, stream>>>(qb, qb + (8u << 20), vb, msk, ctx);
  // output projection + residual
  gemm_nt<1, true><<<dim3(8, 64), blk, 0, stream>>>(ctx, Wob, bo, nullptr, 1024, 1024,
                                                    x, nullptr, y1);
  ln_kernel<<<dim3(8192), blk, 0, stream>>>(y1, g1, be1, hb);
  // FFN
  gemm_nt<2, true><<<dim3(32, 64), blk, 0, stream>>>(hb, W1b, b1, nullptr, 1024, 4096,
                                                     nullptr, ffb, nullptr);
  gemm_nt<1, true><<<dim3(8, 64), blk, 0, stream>>>(ffb, W2b, b2, nullptr, 4096, 1024,
                                                    y1, nullptr, out);
  ln_kernel<<<dim3(8192), blk, 0, stream>>>(out, g2, be2, nullptr);
}